// Round 7
// baseline (1520.038 us; speedup 1.0000x reference)
//
#include <hip/hip_runtime.h>

typedef __bf16 bf16x8 __attribute__((ext_vector_type(8)));
typedef __bf16 bf16x4 __attribute__((ext_vector_type(4)));
typedef float  floatx4 __attribute__((ext_vector_type(4)));

#define GLOBAL_AS __attribute__((address_space(1)))
#define LOCAL_AS  __attribute__((address_space(3)))

static constexpr int HID = 1024;
static constexpr int BK  = 32;        // K per tile
static constexpr int KIT = HID / BK;  // 32 K-tiles

__device__ __forceinline__ void h8(bf16x8& d, float s0, float s1,
                                   const float4& w0a, const float4& w0b,
                                   const float4& w1a, const float4& w1b,
                                   const float4& ba,  const float4& bb) {
    d[0] = (__bf16)fmaxf(fmaf(s1, w1a.x, fmaf(s0, w0a.x, ba.x)), 0.f);
    d[1] = (__bf16)fmaxf(fmaf(s1, w1a.y, fmaf(s0, w0a.y, ba.y)), 0.f);
    d[2] = (__bf16)fmaxf(fmaf(s1, w1a.z, fmaf(s0, w0a.z, ba.z)), 0.f);
    d[3] = (__bf16)fmaxf(fmaf(s1, w1a.w, fmaf(s0, w0a.w, ba.w)), 0.f);
    d[4] = (__bf16)fmaxf(fmaf(s1, w1b.x, fmaf(s0, w0b.x, bb.x)), 0.f);
    d[5] = (__bf16)fmaxf(fmaf(s1, w1b.y, fmaf(s0, w0b.y, bb.y)), 0.f);
    d[6] = (__bf16)fmaxf(fmaf(s1, w1b.z, fmaf(s0, w0b.z, bb.z)), 0.f);
    d[7] = (__bf16)fmaxf(fmaf(s1, w1b.w, fmaf(s0, w0b.w, bb.w)), 0.f);
}

// ---------------------------------------------------------------------------
// prep:
//   [0,256)    zero OUT
//   [256,512)  W2 [K][N] fp32 -> W2T [slab][k-octet 0..127][col 0..255][8] bf16
//              W2T[((slab*128 + ko)*256 + col)*8 + j] = W2[ko*8+j][slab*256+col]
//   [512,544)  W_heads -> WHT[(k>>3)*256 + r*8 + (k&7)], r=s*4+a (<20), else 0
// Octet-major: every quarter-wave of ds_read_b128 / global_load_lds touches
// 16 consecutive 16B slots -> conflict-free, no XOR swizzle.
// ---------------------------------------------------------------------------
__global__ __launch_bounds__(256)
void prep_all(const float* __restrict__ W2, const float* __restrict__ WH,
              __bf16* __restrict__ W2T, __bf16* __restrict__ WHT,
              float* __restrict__ OUT) {
    int b = blockIdx.x;
    if (b < 256) {
        ((float4*)OUT)[(size_t)b * 256 + threadIdx.x]
            = make_float4(0.f, 0.f, 0.f, 0.f);
        return;
    }
    b -= 256;
    if (b < 256) {
        __shared__ __align__(16) __bf16 tile[64][72];  // [col][k], 16B-aligned rows
        const int bx = b & 15;   // 64-col group
        const int by = b >> 4;   // 64-k group (octets by*8 .. by*8+7)
        const int a  = threadIdx.x & 63;
        const int bb = threadIdx.x >> 6;  // 0..3
#pragma unroll
        for (int r = 0; r < 16; ++r) {
            const int k = r * 4 + bb;
            tile[a][k] = (__bf16)W2[(size_t)(by * 64 + k) * HID + bx * 64 + a];
        }
        __syncthreads();
        const int slab = bx >> 2;
#pragma unroll
        for (int p = 0; p < 2; ++p) {
            const int idx  = p * 256 + threadIdx.x;   // 0..511
            const int c    = idx & 63;
            const int oct8 = idx >> 6;                // 0..7
            const bf16x8 v = *(const bf16x8*)&tile[c][oct8 * 8];
            const int col  = (bx & 3) * 64 + c;
            const size_t dst = ((size_t)(slab * 128 + by * 8 + oct8) * 256 + col);
            *(bf16x8*)(W2T + dst * 8) = v;
        }
    } else {
        const int r = b - 256;             // 0..31
        const int s = r >> 2, a = r & 3;
        for (int k = threadIdx.x; k < HID; k += 256) {
            const float v = (r < 20) ? WH[((size_t)s * HID + k) * 4 + a] : 0.f;
            WHT[(size_t)(k >> 3) * 256 + r * 8 + (k & 7)] = (__bf16)v;
        }
    }
}

// ---------------------------------------------------------------------------
// r4's proven 2-barrier body with BK 64 -> 32: LDS 40960 -> 20480 B
// (At [4][64][8] = 4K + Bt [4][256][8] = 16K) -> ~8 blocks/CU instead of 3.
// Theory: the per-tile serial chain (stage -> W1 wait -> h8 -> drain barrier
// -> ds_read -> MFMA) can't be shortened by ILP (r5/r6 refuted); instead we
// overlap it 8-deep across blocks. Per-tile work halves, total identical,
// registers unchanged (~64 VGPR + 64 AGPR -> 8 waves/SIMD fits).
// Head: featL [16][64][8] = 16K overlays Bt; slab done in 2 x 128-col chunks.
// ---------------------------------------------------------------------------
__global__ __launch_bounds__(256, 8)
void policy_main(const float* __restrict__ S,  const int* __restrict__ SK,
                 const float* __restrict__ W1, const float* __restrict__ B1,
                 const __bf16* __restrict__ W2T, const float* __restrict__ B2,
                 const __bf16* __restrict__ WHT, const float* __restrict__ BH,
                 float* __restrict__ OUT) {
    __shared__ __align__(16) char smem[20480];
    __bf16* At    = (__bf16*)smem;            // [4 oct][64 smp][8]  = 4 KiB
    __bf16* Bt    = (__bf16*)(smem + 4096);   // [4 oct][256 col][8] = 16 KiB
    __bf16* featL = (__bf16*)(smem + 4096);   // overlay [16 oct][64 smp][8]

    const int tid  = threadIdx.x;
    const int lane = tid & 63;
    const int wv   = tid >> 6;       // 0..3  (featcol strip of 64; A k-octet)
    const int l15  = lane & 15;
    const int quad = lane >> 4;
    const int slab = blockIdx.x >> 10;      // 0..3 (256-col slab)
    const int g    = blockIdx.x & 1023;     // sample group
    const size_t i0 = (size_t)g * 64;

    floatx4 acc[4][4] = {};   // [fn featcol-frag][fm sample-frag]

    // ---- prologue: this lane's sample state (sample = lane)
    const float2 sv = *(const float2*)(S + (i0 + lane) * 2);

#pragma unroll 1
    for (int kt = 0; kt < KIT; ++kt) {
        __syncthreads();   // previous tile's frag readers done
        // ---- stage B: 4 chunks/wave; chunk c -> octet c>>2, col strip (c&3)*64
#pragma unroll
        for (int L = 0; L < 4; ++L) {
            const int c    = wv * 4 + L;      // 0..15
            const int oct  = c >> 2;
            const int col0 = (c & 3) * 64;
            const __bf16* gp = W2T
                + ((size_t)(slab * 128 + kt * 4 + oct) * 256 + col0 + lane) * 8;
            __builtin_amdgcn_global_load_lds((GLOBAL_AS void*)gp,
                (LOCAL_AS void*)(Bt + (oct * 256 + col0) * 8), 16, 0, 0);
        }
        // ---- compute A tile (H): wave -> k-octet wv, lane -> sample lane
        {
            const float* wp = W1 + kt * BK + wv * 8;
            const float4 w0a = *(const float4*)(wp);
            const float4 w0b = *(const float4*)(wp + 4);
            const float4 w1a = *(const float4*)(wp + HID);
            const float4 w1b = *(const float4*)(wp + HID + 4);
            const float4 ba  = *(const float4*)(B1 + kt * BK + wv * 8);
            const float4 bb  = *(const float4*)(B1 + kt * BK + wv * 8 + 4);
            bf16x8 hv;
            h8(hv, sv.x, sv.y, w0a, w0b, w1a, w1b, ba, bb);
            *(bf16x8*)(At + (wv * 64 + lane) * 8) = hv;
        }
        __syncthreads();   // drain staging + A writes
        // ---- 1 k-step of 32: 8 frag reads + 16 MFMA
        {
            bf16x8 wf[4], hf[4];
#pragma unroll
            for (int f = 0; f < 4; ++f)
                wf[f] = *(const bf16x8*)(Bt
                         + ((quad * 256) + wv * 64 + f * 16 + l15) * 8);
#pragma unroll
            for (int f = 0; f < 4; ++f)
                hf[f] = *(const bf16x8*)(At
                         + ((quad * 64) + f * 16 + l15) * 8);
#pragma unroll
            for (int fn = 0; fn < 4; ++fn)
#pragma unroll
                for (int fm = 0; fm < 4; ++fm)
                    acc[fn][fm] = __builtin_amdgcn_mfma_f32_16x16x32_bf16(
                        wf[fn], hf[fm], acc[fn][fm], 0, 0, 0);
        }
    }

    // ---- head epilogue: 2 x 128-col chunks through 16 KiB featL overlay
    floatx4 hacc[2] = {};
    __syncthreads();   // K-loop frag readers done before overlay
#pragma unroll
    for (int c = 0; c < 2; ++c) {
        if ((wv >> 1) == c) {
#pragma unroll
            for (int fn = 0; fn < 4; ++fn) {
                const int col = wv * 64 + fn * 16 + quad * 4;   // slab-local
                const float4 b2v = *(const float4*)(B2 + slab * 256 + col);
                const int within = col & 127;
                const int o = within >> 3, j = within & 7;
#pragma unroll
                for (int fm = 0; fm < 4; ++fm) {
                    const int smp = fm * 16 + l15;
                    const floatx4 v = acc[fn][fm];
                    bf16x4 p;
                    p[0] = (__bf16)fmaxf(v[0] + b2v.x, 0.f);
                    p[1] = (__bf16)fmaxf(v[1] + b2v.y, 0.f);
                    p[2] = (__bf16)fmaxf(v[2] + b2v.z, 0.f);
                    p[3] = (__bf16)fmaxf(v[3] + b2v.w, 0.f);
                    *(bf16x4*)(featL + (o * 64 + smp) * 8 + j) = p;
                }
            }
        }
        __syncthreads();
        // head MFMA over this chunk's 128 cols; wave wv -> samples wv*16..+15
#pragma unroll
        for (int ks2 = 0; ks2 < 4; ++ks2) {
            const bf16x8 fa = *(const bf16x8*)(featL
                                 + ((ks2 * 4 + quad) * 64 + wv * 16 + l15) * 8);
#pragma unroll
            for (int t2 = 0; t2 < 2; ++t2) {
                const int r  = t2 * 16 + l15;
                const int og = slab * 32 + c * 16 + ks2 * 4 + quad;
                const bf16x8 wb = *(const bf16x8*)(WHT + (size_t)og * 256 + r * 8);
                hacc[t2] = __builtin_amdgcn_mfma_f32_16x16x32_bf16(
                    fa, wb, hacc[t2], 0, 0, 0);
            }
        }
        __syncthreads();
    }

    // ---- atomic scatter: sample = quad*4+reg; emit selected skill's 4 actions
#pragma unroll
    for (int j = 0; j < 4; ++j) {
        const int smp = wv * 16 + quad * 4 + j;
        const int sk  = SK[i0 + smp];
#pragma unroll
        for (int t2 = 0; t2 < 2; ++t2) {
            const int hc = t2 * 16 + l15;
            const int d  = hc - sk * 4;
            if (d >= 0 && d < 4) {
                float v = hacc[t2][j];
                if (slab == 0) v += BH[hc];
                atomicAdd(&OUT[(i0 + smp) * 4 + d], v);
            }
        }
    }
}

extern "C" void kernel_launch(void* const* d_in, const int* in_sizes, int n_in,
                              void* d_out, int out_size, void* d_ws, size_t ws_size,
                              hipStream_t stream) {
    const float* S  = (const float*)d_in[0];
    const int*   SK = (const int*)d_in[1];
    const float* W1 = (const float*)d_in[2];
    const float* B1 = (const float*)d_in[3];
    const float* W2 = (const float*)d_in[4];
    const float* B2 = (const float*)d_in[5];
    const float* WH = (const float*)d_in[6];
    const float* BH = (const float*)d_in[7];

    char* ws = (char*)d_ws;
    __bf16* W2T = (__bf16*)ws;                          // 2 MiB
    __bf16* WHT = (__bf16*)(ws + 2 * 1024 * 1024);      // 64 KiB

    hipLaunchKernelGGL(prep_all, dim3(544), dim3(256), 0, stream,
                       W2, WH, W2T, WHT, (float*)d_out);
    // grid: 1024 sample-groups x 4 slabs; slab = blockIdx>>10 so co-resident
    // blocks share one W2T slab (L2-friendly)
    hipLaunchKernelGGL(policy_main, dim3(4096), dim3(256), 0, stream,
                       S, SK, W1, B1, W2T, B2, WHT, BH, (float*)d_out);
}

// Round 8
// 249.503 us; speedup vs baseline: 6.0923x; 6.0923x over previous
//
#include <hip/hip_runtime.h>

typedef __bf16 bf16x8 __attribute__((ext_vector_type(8)));
typedef __bf16 bf16x4 __attribute__((ext_vector_type(4)));
typedef float  floatx4 __attribute__((ext_vector_type(4)));

#define GLOBAL_AS __attribute__((address_space(1)))
#define LOCAL_AS  __attribute__((address_space(3)))

static constexpr int HID = 1024;
static constexpr int BK  = 32;        // K per tile
static constexpr int KIT = HID / BK;  // 32 K-tiles

__device__ __forceinline__ void h8(bf16x8& d, float s0, float s1,
                                   const float4& w0a, const float4& w0b,
                                   const float4& w1a, const float4& w1b,
                                   const float4& ba,  const float4& bb) {
    d[0] = (__bf16)fmaxf(fmaf(s1, w1a.x, fmaf(s0, w0a.x, ba.x)), 0.f);
    d[1] = (__bf16)fmaxf(fmaf(s1, w1a.y, fmaf(s0, w0a.y, ba.y)), 0.f);
    d[2] = (__bf16)fmaxf(fmaf(s1, w1a.z, fmaf(s0, w0a.z, ba.z)), 0.f);
    d[3] = (__bf16)fmaxf(fmaf(s1, w1a.w, fmaf(s0, w0a.w, ba.w)), 0.f);
    d[4] = (__bf16)fmaxf(fmaf(s1, w1b.x, fmaf(s0, w0b.x, bb.x)), 0.f);
    d[5] = (__bf16)fmaxf(fmaf(s1, w1b.y, fmaf(s0, w0b.y, bb.y)), 0.f);
    d[6] = (__bf16)fmaxf(fmaf(s1, w1b.z, fmaf(s0, w0b.z, bb.z)), 0.f);
    d[7] = (__bf16)fmaxf(fmaf(s1, w1b.w, fmaf(s0, w0b.w, bb.w)), 0.f);
}

// ---------------------------------------------------------------------------
// prep (r7-verified layouts):
//   [0,256)    zero OUT
//   [256,512)  W2 [K][N] fp32 -> W2T [slab][k-octet 0..127][col 0..255][8] bf16
//   [512,544)  W_heads -> WHT[(k>>3)*256 + r*8 + (k&7)], r=s*4+a (<20), else 0
// ---------------------------------------------------------------------------
__global__ __launch_bounds__(256)
void prep_all(const float* __restrict__ W2, const float* __restrict__ WH,
              __bf16* __restrict__ W2T, __bf16* __restrict__ WHT,
              float* __restrict__ OUT) {
    int b = blockIdx.x;
    if (b < 256) {
        ((float4*)OUT)[(size_t)b * 256 + threadIdx.x]
            = make_float4(0.f, 0.f, 0.f, 0.f);
        return;
    }
    b -= 256;
    if (b < 256) {
        __shared__ __align__(16) __bf16 tile[64][72];
        const int bx = b & 15;   // 64-col group
        const int by = b >> 4;   // 64-k group
        const int a  = threadIdx.x & 63;
        const int bb = threadIdx.x >> 6;  // 0..3
#pragma unroll
        for (int r = 0; r < 16; ++r) {
            const int k = r * 4 + bb;
            tile[a][k] = (__bf16)W2[(size_t)(by * 64 + k) * HID + bx * 64 + a];
        }
        __syncthreads();
        const int slab = bx >> 2;
#pragma unroll
        for (int p = 0; p < 2; ++p) {
            const int idx  = p * 256 + threadIdx.x;   // 0..511
            const int c    = idx & 63;
            const int oct8 = idx >> 6;                // 0..7
            const bf16x8 v = *(const bf16x8*)&tile[c][oct8 * 8];
            const int col  = (bx & 3) * 64 + c;
            const size_t dst = ((size_t)(slab * 128 + by * 8 + oct8) * 256 + col);
            *(bf16x8*)(W2T + dst * 8) = v;
        }
    } else {
        const int r = b - 256;             // 0..31
        const int s = r >> 2, a = r & 3;
        for (int k = threadIdx.x; k < HID; k += 256) {
            const float v = (r < 20) ? WH[((size_t)s * HID + k) * 4 + a] : 0.f;
            WHT[(size_t)(k >> 3) * 256 + r * 8 + (k & 7)] = (__bf16)v;
        }
    }
}

// ---------------------------------------------------------------------------
// T3 "minimum 2-phase" schedule on the r4/r7 geometry (64x256 tile, 4 waves):
//   - W1/B1 cached in LDS ONCE per block (12 KiB): h8 operands become
//     wave-uniform ds_read broadcasts (~120 cyc, no vmcnt) instead of a
//     per-tile L2 round-trip in the barrier-synced path (r4's stall).
//   - A and B double-buffered; per tile t: {stage B[t+1] -> Bb[nxt];
//     h8 -> A[nxt]; frag-read cur; 16 MFMA; ONE __syncthreads()}. The
//     barrier's vmcnt(0) drain waits on loads issued a full phase earlier.
//   - Barrier count halves vs r4 (32 vs 2x16); zero persistent registers
//     added (r5/r6/r7 failure mode avoided).
// LDS: W1L 8K @0, B1L 4K @8192, A dbuf 2x4K @12288, B dbuf 2x16K @20480
//      = 53248 B -> 3 blocks/CU. featL head overlay 16K @20480.
// ---------------------------------------------------------------------------
__global__ __launch_bounds__(256, 3)
void policy_main(const float* __restrict__ S,  const int* __restrict__ SK,
                 const float* __restrict__ W1, const float* __restrict__ B1,
                 const __bf16* __restrict__ W2T, const float* __restrict__ B2,
                 const __bf16* __restrict__ WHT, const float* __restrict__ BH,
                 float* __restrict__ OUT) {
    __shared__ __align__(16) char smem[53248];
    float*  W1L   = (float*)smem;              // [2][1024] f32 = 8 KiB
    float*  B1L   = (float*)(smem + 8192);     // [1024] f32    = 4 KiB
    __bf16* At    = (__bf16*)(smem + 12288);   // 2 x [4 oct][64 smp][8]
    __bf16* Bt    = (__bf16*)(smem + 20480);   // 2 x [4 oct][256 col][8]
    __bf16* featL = (__bf16*)(smem + 20480);   // overlay [16 oct][64 smp][8]

    const int tid  = threadIdx.x;
    const int lane = tid & 63;
    const int wv   = tid >> 6;       // 0..3 (featcol strip of 64; A k-octet)
    const int l15  = lane & 15;
    const int quad = lane >> 4;
    const int slab = blockIdx.x >> 10;      // 0..3 (256-col slab)
    const int g    = blockIdx.x & 1023;     // sample group
    const size_t i0 = (size_t)g * 64;

    floatx4 acc[4][4] = {};   // [fn featcol-frag][fm sample-frag]

    // ---- prologue: sample state (sample = lane)
    const float2 sv = *(const float2*)(S + (i0 + lane) * 2);

    // ---- prologue: stage W1(8K)+B1(4K) into LDS as 12 x 1 KiB chunks
#pragma unroll
    for (int L = 0; L < 3; ++L) {
        const int cc = wv * 3 + L;           // 0..11
        const float* gp = (cc < 8) ? (W1 + cc * 256 + lane * 4)
                                   : (B1 + (cc - 8) * 256 + lane * 4);
        __builtin_amdgcn_global_load_lds((GLOBAL_AS void*)gp,
            (LOCAL_AS void*)(smem + cc * 1024), 16, 0, 0);
    }
    // ---- prologue: stage B[0] into Bt buf 0
#pragma unroll
    for (int L = 0; L < 4; ++L) {
        const int c    = wv * 4 + L;
        const int oct  = c >> 2;
        const int col0 = (c & 3) * 64;
        const __bf16* gp = W2T
            + ((size_t)(slab * 128 + oct) * 256 + col0 + lane) * 8;
        __builtin_amdgcn_global_load_lds((GLOBAL_AS void*)gp,
            (LOCAL_AS void*)(Bt + (oct * 256 + col0) * 8), 16, 0, 0);
    }
    __syncthreads();   // W1L + B[0] landed (full drain, prologue-only cost)

    // ---- prologue: compute A[0] (W1 slab from LDS, wave-uniform broadcast)
    {
        const float4 w0a = *(const float4*)(W1L + wv * 8);
        const float4 w0b = *(const float4*)(W1L + wv * 8 + 4);
        const float4 w1a = *(const float4*)(W1L + 1024 + wv * 8);
        const float4 w1b = *(const float4*)(W1L + 1024 + wv * 8 + 4);
        const float4 ba  = *(const float4*)(B1L + wv * 8);
        const float4 bb  = *(const float4*)(B1L + wv * 8 + 4);
        bf16x8 hv;
        h8(hv, sv.x, sv.y, w0a, w0b, w1a, w1b, ba, bb);
        *(bf16x8*)(At + (wv * 64 + lane) * 8) = hv;
    }
    __syncthreads();   // A[0] visible

#pragma unroll 1
    for (int t = 0; t < KIT; ++t) {
        const int cur = t & 1, nxt = cur ^ 1;
        const __bf16* Ac = At + cur * 2048;
        __bf16*       An = At + nxt * 2048;
        const __bf16* Bc = Bt + cur * 8192;
        __bf16*       Bn = Bt + nxt * 8192;

        if (t + 1 < KIT) {
            // ---- stage B[t+1] (issued a full phase before its use-drain)
#pragma unroll
            for (int L = 0; L < 4; ++L) {
                const int c    = wv * 4 + L;
                const int oct  = c >> 2;
                const int col0 = (c & 3) * 64;
                const __bf16* gp = W2T
                    + ((size_t)(slab * 128 + (t + 1) * 4 + oct) * 256 + col0 + lane) * 8;
                __builtin_amdgcn_global_load_lds((GLOBAL_AS void*)gp,
                    (LOCAL_AS void*)(Bn + (oct * 256 + col0) * 8), 16, 0, 0);
            }
            // ---- compute A[t+1]: W1 slab via LDS broadcast (no vmcnt)
            const int k0 = (t + 1) * BK + wv * 8;
            const float4 w0a = *(const float4*)(W1L + k0);
            const float4 w0b = *(const float4*)(W1L + k0 + 4);
            const float4 w1a = *(const float4*)(W1L + 1024 + k0);
            const float4 w1b = *(const float4*)(W1L + 1024 + k0 + 4);
            const float4 ba  = *(const float4*)(B1L + k0);
            const float4 bb  = *(const float4*)(B1L + k0 + 4);
            bf16x8 hv;
            h8(hv, sv.x, sv.y, w0a, w0b, w1a, w1b, ba, bb);
            *(bf16x8*)(An + (wv * 64 + lane) * 8) = hv;
        }

        // ---- frag reads + 16 MFMA on current buffers
        {
            bf16x8 wf[4], hf[4];
#pragma unroll
            for (int f = 0; f < 4; ++f)
                wf[f] = *(const bf16x8*)(Bc
                         + ((quad * 256) + wv * 64 + f * 16 + l15) * 8);
#pragma unroll
            for (int f = 0; f < 4; ++f)
                hf[f] = *(const bf16x8*)(Ac
                         + ((quad * 64) + f * 16 + l15) * 8);
#pragma unroll
            for (int fn = 0; fn < 4; ++fn)
#pragma unroll
                for (int fm = 0; fm < 4; ++fm)
                    acc[fn][fm] = __builtin_amdgcn_mfma_f32_16x16x32_bf16(
                        wf[fn], hf[fm], acc[fn][fm], 0, 0, 0);
        }
        __syncthreads();   // one barrier/tile: next-tile A+B ready, cur reads done
    }

    // ---- head epilogue: 2 x 128-col chunks through featL overlay (r7 form)
    floatx4 hacc[2] = {};
#pragma unroll
    for (int c = 0; c < 2; ++c) {
        if ((wv >> 1) == c) {
#pragma unroll
            for (int fn = 0; fn < 4; ++fn) {
                const int col = wv * 64 + fn * 16 + quad * 4;   // slab-local
                const float4 b2v = *(const float4*)(B2 + slab * 256 + col);
                const int within = col & 127;
                const int o = within >> 3, j = within & 7;
#pragma unroll
                for (int fm = 0; fm < 4; ++fm) {
                    const int smp = fm * 16 + l15;
                    const floatx4 v = acc[fn][fm];
                    bf16x4 p;
                    p[0] = (__bf16)fmaxf(v[0] + b2v.x, 0.f);
                    p[1] = (__bf16)fmaxf(v[1] + b2v.y, 0.f);
                    p[2] = (__bf16)fmaxf(v[2] + b2v.z, 0.f);
                    p[3] = (__bf16)fmaxf(v[3] + b2v.w, 0.f);
                    *(bf16x4*)(featL + (o * 64 + smp) * 8 + j) = p;
                }
            }
        }
        __syncthreads();
#pragma unroll
        for (int ks2 = 0; ks2 < 4; ++ks2) {
            const bf16x8 fa = *(const bf16x8*)(featL
                                 + ((ks2 * 4 + quad) * 64 + wv * 16 + l15) * 8);
#pragma unroll
            for (int t2 = 0; t2 < 2; ++t2) {
                const int r  = t2 * 16 + l15;
                const int og = slab * 32 + c * 16 + ks2 * 4 + quad;
                const bf16x8 wb = *(const bf16x8*)(WHT + (size_t)og * 256 + r * 8);
                hacc[t2] = __builtin_amdgcn_mfma_f32_16x16x32_bf16(
                    fa, wb, hacc[t2], 0, 0, 0);
            }
        }
        __syncthreads();
    }

    // ---- atomic scatter: sample = quad*4+reg; emit selected skill's 4 actions
#pragma unroll
    for (int j = 0; j < 4; ++j) {
        const int smp = wv * 16 + quad * 4 + j;
        const int sk  = SK[i0 + smp];
#pragma unroll
        for (int t2 = 0; t2 < 2; ++t2) {
            const int hc = t2 * 16 + l15;
            const int d  = hc - sk * 4;
            if (d >= 0 && d < 4) {
                float v = hacc[t2][j];
                if (slab == 0) v += BH[hc];
                atomicAdd(&OUT[(i0 + smp) * 4 + d], v);
            }
        }
    }
}

extern "C" void kernel_launch(void* const* d_in, const int* in_sizes, int n_in,
                              void* d_out, int out_size, void* d_ws, size_t ws_size,
                              hipStream_t stream) {
    const float* S  = (const float*)d_in[0];
    const int*   SK = (const int*)d_in[1];
    const float* W1 = (const float*)d_in[2];
    const float* B1 = (const float*)d_in[3];
    const float* W2 = (const float*)d_in[4];
    const float* B2 = (const float*)d_in[5];
    const float* WH = (const float*)d_in[6];
    const float* BH = (const float*)d_in[7];

    char* ws = (char*)d_ws;
    __bf16* W2T = (__bf16*)ws;                          // 2 MiB
    __bf16* WHT = (__bf16*)(ws + 2 * 1024 * 1024);      // 64 KiB

    hipLaunchKernelGGL(prep_all, dim3(544), dim3(256), 0, stream,
                       W2, WH, W2T, WHT, (float*)d_out);
    // grid: 1024 sample-groups x 4 slabs; slab = blockIdx>>10 so co-resident
    // blocks share one W2T slab (L2-friendly)
    hipLaunchKernelGGL(policy_main, dim3(4096), dim3(256), 0, stream,
                       S, SK, W1, B1, W2T, B2, WHT, BH, (float*)d_out);
}

// Round 10
// 220.872 us; speedup vs baseline: 6.8820x; 1.1296x over previous
//
#include <hip/hip_runtime.h>

typedef __bf16 bf16x8 __attribute__((ext_vector_type(8)));
typedef __bf16 bf16x4 __attribute__((ext_vector_type(4)));
typedef float  floatx4 __attribute__((ext_vector_type(4)));

#define GLOBAL_AS __attribute__((address_space(1)))
#define LOCAL_AS  __attribute__((address_space(3)))

static constexpr int HID = 1024;
static constexpr int BK  = 64;        // K per tile
static constexpr int KIT = HID / BK;  // 16 K-tiles

__device__ __forceinline__ void h8(bf16x8& d, float s0, float s1,
                                   const float4& w0a, const float4& w0b,
                                   const float4& w1a, const float4& w1b,
                                   const float4& ba,  const float4& bb) {
    d[0] = (__bf16)fmaxf(fmaf(s1, w1a.x, fmaf(s0, w0a.x, ba.x)), 0.f);
    d[1] = (__bf16)fmaxf(fmaf(s1, w1a.y, fmaf(s0, w0a.y, ba.y)), 0.f);
    d[2] = (__bf16)fmaxf(fmaf(s1, w1a.z, fmaf(s0, w0a.z, ba.z)), 0.f);
    d[3] = (__bf16)fmaxf(fmaf(s1, w1a.w, fmaf(s0, w0a.w, ba.w)), 0.f);
    d[4] = (__bf16)fmaxf(fmaf(s1, w1b.x, fmaf(s0, w0b.x, bb.x)), 0.f);
    d[5] = (__bf16)fmaxf(fmaf(s1, w1b.y, fmaf(s0, w0b.y, bb.y)), 0.f);
    d[6] = (__bf16)fmaxf(fmaf(s1, w1b.z, fmaf(s0, w0b.z, bb.z)), 0.f);
    d[7] = (__bf16)fmaxf(fmaf(s1, w1b.w, fmaf(s0, w0b.w, bb.w)), 0.f);
}

// ---------------------------------------------------------------------------
// prep (r4-verified layouts, byte-identical):
//   [0,256)    zero OUT
//   [256,512)  W2 [K][N] fp32 -> W2T K-octet-major bf16:
//              W2T[(((slab*16+kt)*8+oct)*256+col)*8 + j]
//                = W2[kt*64+oct*8+j][slab*256+col]
//   [512,544)  W_heads -> WHT[(k>>3)*256 + r*8 + (k&7)], r=s*4+a (<20), else 0
// ---------------------------------------------------------------------------
__global__ __launch_bounds__(256)
void prep_all(const float* __restrict__ W2, const float* __restrict__ WH,
              __bf16* __restrict__ W2T, __bf16* __restrict__ WHT,
              float* __restrict__ OUT) {
    int b = blockIdx.x;
    if (b < 256) {
        ((float4*)OUT)[(size_t)b * 256 + threadIdx.x]
            = make_float4(0.f, 0.f, 0.f, 0.f);
        return;
    }
    b -= 256;
    if (b < 256) {
        __shared__ __align__(16) __bf16 tile[64][72];  // [col][k], 16B-aligned rows
        const int bx = b & 15;   // 64-col group
        const int by = b >> 4;   // 64-k group (= kt)
        const int a  = threadIdx.x & 63;
        const int bb = threadIdx.x >> 6;  // 0..3
#pragma unroll
        for (int r = 0; r < 16; ++r) {
            const int k = r * 4 + bb;
            tile[a][k] = (__bf16)W2[(size_t)(by * 64 + k) * HID + bx * 64 + a];
        }
        __syncthreads();
        const int slab = bx >> 2;
#pragma unroll
        for (int p = 0; p < 2; ++p) {
            const int idx = p * 256 + threadIdx.x;   // 0..511
            const int c   = idx & 63;
            const int oct = idx >> 6;                // 0..7
            const bf16x8 v = *(const bf16x8*)&tile[c][oct * 8];
            const int col = (bx & 3) * 64 + c;
            const size_t dst = ((size_t)(slab * KIT + by) * 8 + oct) * 256 + col;
            *(bf16x8*)(W2T + dst * 8) = v;
        }
    } else {
        const int r = b - 256;             // 0..31
        const int s = r >> 2, a = r & 3;
        for (int k = threadIdx.x; k < HID; k += 256) {
            const float v = (r < 20) ? WH[((size_t)s * HID + k) * 4 + a] : 0.f;
            WHT[(size_t)(k >> 3) * 256 + r * 8 + (k & 7)] = (__bf16)v;
        }
    }
}

// ---------------------------------------------------------------------------
// r4 champion structure (64x256 tile, 4 waves, 2-barrier K-loop, 40960 B LDS,
// 3 blocks/CU, 169 us main) with ONE change: the W1/B1 float4 loads are
// issued BEFORE the 8 B-staging global_load_lds. vmcnt is a queue: waiting
// for W1 (oldest) is then vmcnt(8) -- the staging loads STAY IN FLIGHT while
// h8's ~200-cyc VALU burst runs, so the __syncthreads drain afterwards finds
// them already landed. In r4's order (stages first), h8's W1-wait was
// vmcnt(0), which drained the whole staging queue before any h8 FMA --
// the exposed per-tile serial chain that r5/r6/r8's register/LDS attempts
// failed to remove. This fix costs zero registers and zero structure.
// (Resubmission of round 9 — the bench infra failed; theory untested.)
// ---------------------------------------------------------------------------
__global__ __launch_bounds__(256, 3)
void policy_main(const float* __restrict__ S,  const int* __restrict__ SK,
                 const float* __restrict__ W1, const float* __restrict__ B1,
                 const __bf16* __restrict__ W2T, const float* __restrict__ B2,
                 const __bf16* __restrict__ WHT, const float* __restrict__ BH,
                 float* __restrict__ OUT) {
    __shared__ __align__(16) char smem[40960];
    __bf16* At    = (__bf16*)smem;            // [8 oct][64 smp][8]  = 8 KiB
    __bf16* Bt    = (__bf16*)(smem + 8192);   // [8 oct][256 col][8] = 32 KiB
    __bf16* featL = (__bf16*)(smem + 8192);   // overlay [32 oct][64 smp][8]

    const int tid  = threadIdx.x;
    const int lane = tid & 63;
    const int wv   = tid >> 6;       // 0..3  (featcol strip of 64)
    const int l15  = lane & 15;
    const int quad = lane >> 4;
    const int slab = blockIdx.x >> 10;      // 0..3 (256-col slab)
    const int g    = blockIdx.x & 1023;     // sample group
    const size_t i0 = (size_t)g * 64;

    const int octA = wv * 2 + (lane >> 5);  // A-compute k-octet
    const int smpA = lane & 31;             // A-compute sample

    floatx4 acc[4][4] = {};   // [fn featcol-frag][fm sample-frag]

    // ---- prologue: this lane's 2 sample states
    const float2 sv0 = *(const float2*)(S + (i0 + smpA) * 2);
    const float2 sv1 = *(const float2*)(S + (i0 + 32 + smpA) * 2);

#pragma unroll 1
    for (int kt = 0; kt < KIT; ++kt) {
        __syncthreads();   // previous tile's frag readers done
        // ---- W1/B1 slab loads FIRST (oldest in vmcnt queue): h8's use-wait
        //      becomes vmcnt(8), leaving the 8 staging loads in flight.
        const float* wp = W1 + kt * BK + octA * 8;
        const float4 w0a = *(const float4*)(wp);
        const float4 w0b = *(const float4*)(wp + 4);
        const float4 w1a = *(const float4*)(wp + HID);
        const float4 w1b = *(const float4*)(wp + HID + 4);
        const float4 ba  = *(const float4*)(B1 + kt * BK + octA * 8);
        const float4 bb  = *(const float4*)(B1 + kt * BK + octA * 8 + 4);
        // ---- stage B: 8 chunks/wave; wave -> col strip wv*64, chunk L -> oct
#pragma unroll
        for (int L = 0; L < 8; ++L) {
            const __bf16* gp = W2T
                + (((size_t)(slab * KIT + kt) * 8 + L) * 256 + wv * 64 + lane) * 8;
            __builtin_amdgcn_global_load_lds((GLOBAL_AS void*)gp,
                (LOCAL_AS void*)(Bt + (L * 256 + wv * 64) * 8), 16, 0, 0);
        }
        // ---- compute A tile (H): lane -> octet octA, samples smpA, smpA+32
        {
            bf16x8 hv;
            h8(hv, sv0.x, sv0.y, w0a, w0b, w1a, w1b, ba, bb);
            *(bf16x8*)(At + (octA * 64 + smpA) * 8) = hv;
            h8(hv, sv1.x, sv1.y, w0a, w0b, w1a, w1b, ba, bb);
            *(bf16x8*)(At + (octA * 64 + 32 + smpA) * 8) = hv;
        }
        __syncthreads();   // drain staging + A writes
        // ---- 2 k-steps of 32: 8 frag reads + 16 MFMA each
#pragma unroll
        for (int ks = 0; ks < 2; ++ks) {
            bf16x8 wf[4], hf[4];
#pragma unroll
            for (int f = 0; f < 4; ++f)
                wf[f] = *(const bf16x8*)(Bt
                         + (((ks * 4 + quad) * 256) + wv * 64 + f * 16 + l15) * 8);
#pragma unroll
            for (int f = 0; f < 4; ++f)
                hf[f] = *(const bf16x8*)(At
                         + (((ks * 4 + quad) * 64) + f * 16 + l15) * 8);
#pragma unroll
            for (int fn = 0; fn < 4; ++fn)
#pragma unroll
                for (int fm = 0; fm < 4; ++fm)
                    acc[fn][fm] = __builtin_amdgcn_mfma_f32_16x16x32_bf16(
                        wf[fn], hf[fm], acc[fn][fm], 0, 0, 0);
        }
    }

    // ---- epilogue: relu(acc + b2) -> featL (K-octet-major overlay over Bt)
    __syncthreads();
#pragma unroll
    for (int fn = 0; fn < 4; ++fn) {
        const int fcb = wv * 64 + fn * 16 + quad * 4;   // featcol base
        const float4 b2v = *(const float4*)(B2 + slab * 256 + fcb);
        const int o = fcb >> 3, j = fcb & 7;
#pragma unroll
        for (int fm = 0; fm < 4; ++fm) {
            const int smp = fm * 16 + l15;
            const floatx4 v = acc[fn][fm];
            bf16x4 p;
            p[0] = (__bf16)fmaxf(v[0] + b2v.x, 0.f);
            p[1] = (__bf16)fmaxf(v[1] + b2v.y, 0.f);
            p[2] = (__bf16)fmaxf(v[2] + b2v.z, 0.f);
            p[3] = (__bf16)fmaxf(v[3] + b2v.w, 0.f);
            *(bf16x4*)(featL + (o * 64 + smp) * 8 + j) = p;
        }
    }
    __syncthreads();

    // ---- head MFMA: wave wv -> samples wv*16..+15; WHT direct (L2-hot)
    floatx4 hacc[2] = {};
#pragma unroll
    for (int ks2 = 0; ks2 < 8; ++ks2) {
        const bf16x8 fa = *(const bf16x8*)(featL
                             + ((ks2 * 4 + quad) * 64 + wv * 16 + l15) * 8);
#pragma unroll
        for (int t2 = 0; t2 < 2; ++t2) {
            const int r  = t2 * 16 + l15;
            const int og = slab * 32 + ks2 * 4 + quad;
            const bf16x8 wb = *(const bf16x8*)(WHT + (size_t)og * 256 + r * 8);
            hacc[t2] = __builtin_amdgcn_mfma_f32_16x16x32_bf16(
                fa, wb, hacc[t2], 0, 0, 0);
        }
    }

    // ---- atomic scatter: sample = quad*4+reg; emit selected skill's 4 actions
#pragma unroll
    for (int j = 0; j < 4; ++j) {
        const int smp = wv * 16 + quad * 4 + j;
        const int sk  = SK[i0 + smp];
#pragma unroll
        for (int t2 = 0; t2 < 2; ++t2) {
            const int hc = t2 * 16 + l15;
            const int d  = hc - sk * 4;
            if (d >= 0 && d < 4) {
                float v = hacc[t2][j];
                if (slab == 0) v += BH[hc];
                atomicAdd(&OUT[(i0 + smp) * 4 + d], v);
            }
        }
    }
}

extern "C" void kernel_launch(void* const* d_in, const int* in_sizes, int n_in,
                              void* d_out, int out_size, void* d_ws, size_t ws_size,
                              hipStream_t stream) {
    const float* S  = (const float*)d_in[0];
    const int*   SK = (const int*)d_in[1];
    const float* W1 = (const float*)d_in[2];
    const float* B1 = (const float*)d_in[3];
    const float* W2 = (const float*)d_in[4];
    const float* B2 = (const float*)d_in[5];
    const float* WH = (const float*)d_in[6];
    const float* BH = (const float*)d_in[7];

    char* ws = (char*)d_ws;
    __bf16* W2T = (__bf16*)ws;                          // 2 MiB
    __bf16* WHT = (__bf16*)(ws + 2 * 1024 * 1024);      // 64 KiB

    hipLaunchKernelGGL(prep_all, dim3(544), dim3(256), 0, stream,
                       W2, WH, W2T, WHT, (float*)d_out);
    // grid: 1024 sample-groups x 4 slabs; slab = blockIdx>>10 so co-resident
    // blocks share one W2T slab (L2-friendly)
    hipLaunchKernelGGL(policy_main, dim3(4096), dim3(256), 0, stream,
                       S, SK, W1, B1, W2T, B2, WHT, BH, (float*)d_out);
}

// Round 11
// 215.639 us; speedup vs baseline: 7.0490x; 1.0243x over previous
//
#include <hip/hip_runtime.h>

typedef __bf16 bf16x8 __attribute__((ext_vector_type(8)));
typedef __bf16 bf16x4 __attribute__((ext_vector_type(4)));
typedef float  floatx4 __attribute__((ext_vector_type(4)));

#define GLOBAL_AS __attribute__((address_space(1)))
#define LOCAL_AS  __attribute__((address_space(3)))

static constexpr int HID = 1024;
static constexpr int BK  = 64;        // K per tile
static constexpr int KIT = HID / BK;  // 16 K-tiles

__device__ __forceinline__ void h8(bf16x8& d, float s0, float s1,
                                   const float4& w0a, const float4& w0b,
                                   const float4& w1a, const float4& w1b,
                                   const float4& ba,  const float4& bb) {
    d[0] = (__bf16)fmaxf(fmaf(s1, w1a.x, fmaf(s0, w0a.x, ba.x)), 0.f);
    d[1] = (__bf16)fmaxf(fmaf(s1, w1a.y, fmaf(s0, w0a.y, ba.y)), 0.f);
    d[2] = (__bf16)fmaxf(fmaf(s1, w1a.z, fmaf(s0, w0a.z, ba.z)), 0.f);
    d[3] = (__bf16)fmaxf(fmaf(s1, w1a.w, fmaf(s0, w0a.w, ba.w)), 0.f);
    d[4] = (__bf16)fmaxf(fmaf(s1, w1b.x, fmaf(s0, w0b.x, bb.x)), 0.f);
    d[5] = (__bf16)fmaxf(fmaf(s1, w1b.y, fmaf(s0, w0b.y, bb.y)), 0.f);
    d[6] = (__bf16)fmaxf(fmaf(s1, w1b.z, fmaf(s0, w0b.z, bb.z)), 0.f);
    d[7] = (__bf16)fmaxf(fmaf(s1, w1b.w, fmaf(s0, w0b.w, bb.w)), 0.f);
}

// ---------------------------------------------------------------------------
// prep (r4/r10-verified layouts, byte-identical):
//   [0,256)    zero OUT
//   [256,512)  W2 [K][N] fp32 -> W2T K-octet-major bf16:
//              W2T[(((slab*16+kt)*8+oct)*256+col)*8 + j]
//                = W2[kt*64+oct*8+j][slab*256+col]
//   [512,544)  W_heads -> WHT[(k>>3)*256 + r*8 + (k&7)], r=s*4+a (<20), else 0
// ---------------------------------------------------------------------------
__global__ __launch_bounds__(256)
void prep_all(const float* __restrict__ W2, const float* __restrict__ WH,
              __bf16* __restrict__ W2T, __bf16* __restrict__ WHT,
              float* __restrict__ OUT) {
    int b = blockIdx.x;
    if (b < 256) {
        ((float4*)OUT)[(size_t)b * 256 + threadIdx.x]
            = make_float4(0.f, 0.f, 0.f, 0.f);
        return;
    }
    b -= 256;
    if (b < 256) {
        __shared__ __align__(16) __bf16 tile[64][72];  // [col][k], 16B-aligned rows
        const int bx = b & 15;   // 64-col group
        const int by = b >> 4;   // 64-k group (= kt)
        const int a  = threadIdx.x & 63;
        const int bb = threadIdx.x >> 6;  // 0..3
#pragma unroll
        for (int r = 0; r < 16; ++r) {
            const int k = r * 4 + bb;
            tile[a][k] = (__bf16)W2[(size_t)(by * 64 + k) * HID + bx * 64 + a];
        }
        __syncthreads();
        const int slab = bx >> 2;
#pragma unroll
        for (int p = 0; p < 2; ++p) {
            const int idx = p * 256 + threadIdx.x;   // 0..511
            const int c   = idx & 63;
            const int oct = idx >> 6;                // 0..7
            const bf16x8 v = *(const bf16x8*)&tile[c][oct * 8];
            const int col = (bx & 3) * 64 + c;
            const size_t dst = ((size_t)(slab * KIT + by) * 8 + oct) * 256 + col;
            *(bf16x8*)(W2T + dst * 8) = v;
        }
    } else {
        const int r = b - 256;             // 0..31
        const int s = r >> 2, a = r & 3;
        for (int k = threadIdx.x; k < HID; k += 256) {
            const float v = (r < 20) ? WH[((size_t)s * HID + k) * 4 + a] : 0.f;
            WHT[(size_t)(k >> 3) * 256 + r * 8 + (k & 7)] = (__bf16)v;
        }
    }
}

// ---------------------------------------------------------------------------
// r10 champion with the B-side LDS round-trip DELETED. Measured-pipe math
// (r10): DS pipe ~71% busy (64 ds_read_b128 + 32KB staging-write + At writes
// per tile per block) -- the hidden limiter behind the 169us plateau. Each
// Bt element was read exactly ONCE, so staging bought nothing: wf now loads
// DIRECTLY from W2T (L2-hot, 16B/lane, 4x256B segments per inst) into
// registers. Removes per tile: 8 global_load_lds, 32 KB Bt, 32 wave
// ds_reads, the staging vmcnt(0) drain, and one of the two barriers.
//   tile kt: W1[kt+1] loads (oldest) -> 8 wf global loads -> h8 -> At[nxt]
//            ds_write -> {2x (4 hf ds_read + 16 MFMA)} -> __syncthreads.
// At double-buffered (2x8K); featL head overlay 32K; LDS total 32768 B.
// DS traffic drops ~62%; one barrier per tile; all VMEM consumed pre-barrier
// so the __syncthreads drain is free.
// ---------------------------------------------------------------------------
__global__ __launch_bounds__(256, 3)
void policy_main(const float* __restrict__ S,  const int* __restrict__ SK,
                 const float* __restrict__ W1, const float* __restrict__ B1,
                 const __bf16* __restrict__ W2T, const float* __restrict__ B2,
                 const __bf16* __restrict__ WHT, const float* __restrict__ BH,
                 float* __restrict__ OUT) {
    __shared__ __align__(16) char smem[32768];
    __bf16* At    = (__bf16*)smem;            // 2 x [8 oct][64 smp][8] = 16 KiB
    __bf16* featL = (__bf16*)smem;            // overlay [32 oct][64 smp][8] = 32K

    const int tid  = threadIdx.x;
    const int lane = tid & 63;
    const int wv   = tid >> 6;       // 0..3  (featcol strip of 64)
    const int l15  = lane & 15;
    const int quad = lane >> 4;
    const int slab = blockIdx.x >> 10;      // 0..3 (256-col slab)
    const int g    = blockIdx.x & 1023;     // sample group
    const size_t i0 = (size_t)g * 64;

    const int octA = wv * 2 + (lane >> 5);  // A-compute k-octet
    const int smpA = lane & 31;             // A-compute sample

    floatx4 acc[4][4] = {};   // [fn featcol-frag][fm sample-frag]

    // ---- prologue: this lane's 2 sample states
    const float2 sv0 = *(const float2*)(S + (i0 + smpA) * 2);
    const float2 sv1 = *(const float2*)(S + (i0 + 32 + smpA) * 2);

    // ---- prologue: compute A[0] -> At buf 0
    {
        const float* wp = W1 + octA * 8;
        const float4 w0a = *(const float4*)(wp);
        const float4 w0b = *(const float4*)(wp + 4);
        const float4 w1a = *(const float4*)(wp + HID);
        const float4 w1b = *(const float4*)(wp + HID + 4);
        const float4 ba  = *(const float4*)(B1 + octA * 8);
        const float4 bb  = *(const float4*)(B1 + octA * 8 + 4);
        bf16x8 hv;
        h8(hv, sv0.x, sv0.y, w0a, w0b, w1a, w1b, ba, bb);
        *(bf16x8*)(At + (octA * 64 + smpA) * 8) = hv;
        h8(hv, sv1.x, sv1.y, w0a, w0b, w1a, w1b, ba, bb);
        *(bf16x8*)(At + (octA * 64 + 32 + smpA) * 8) = hv;
    }
    __syncthreads();   // At[0] visible

    // per-lane W2T fragment base: octet o reads at +o*2048 elems, ks at quad
    const __bf16* wbase = W2T + ((size_t)(slab * KIT) * 8 + quad) * 2048
                        + (wv * 64 + l15) * 8;

#pragma unroll 1
    for (int kt = 0; kt < KIT; ++kt) {
        const __bf16* Ac = At + (kt & 1) * 4096;
        __bf16*       An = At + ((kt + 1) & 1) * 4096;

        // ---- W1/B1 loads for NEXT tile first (oldest in vm queue)
        float4 w0a, w0b, w1a, w1b, ba, bb;
        if (kt + 1 < KIT) {
            const float* wp = W1 + (kt + 1) * BK + octA * 8;
            w0a = *(const float4*)(wp);
            w0b = *(const float4*)(wp + 4);
            w1a = *(const float4*)(wp + HID);
            w1b = *(const float4*)(wp + HID + 4);
            ba  = *(const float4*)(B1 + (kt + 1) * BK + octA * 8);
            bb  = *(const float4*)(B1 + (kt + 1) * BK + octA * 8 + 4);
        }
        // ---- wf: 8 direct global loads from W2T (L2-hot), issued early
        bf16x8 wf0[4], wf1[4];
        const __bf16* wkt = wbase + (size_t)kt * 8 * 2048;
#pragma unroll
        for (int f = 0; f < 4; ++f)
            wf0[f] = *(const bf16x8*)(wkt + f * 16 * 8);                 // ks=0
#pragma unroll
        for (int f = 0; f < 4; ++f)
            wf1[f] = *(const bf16x8*)(wkt + 4 * 2048 + f * 16 * 8);      // ks=1
        // ---- h8 -> At[nxt] (waits only on W1: vmcnt leaves wf in flight)
        if (kt + 1 < KIT) {
            bf16x8 hv;
            h8(hv, sv0.x, sv0.y, w0a, w0b, w1a, w1b, ba, bb);
            *(bf16x8*)(An + (octA * 64 + smpA) * 8) = hv;
            h8(hv, sv1.x, sv1.y, w0a, w0b, w1a, w1b, ba, bb);
            *(bf16x8*)(An + (octA * 64 + 32 + smpA) * 8) = hv;
        }
        // ---- ks=0: 4 hf ds_reads + 16 MFMA
        {
            bf16x8 hf[4];
#pragma unroll
            for (int f = 0; f < 4; ++f)
                hf[f] = *(const bf16x8*)(Ac + ((quad * 64) + f * 16 + l15) * 8);
#pragma unroll
            for (int fn = 0; fn < 4; ++fn)
#pragma unroll
                for (int fm = 0; fm < 4; ++fm)
                    acc[fn][fm] = __builtin_amdgcn_mfma_f32_16x16x32_bf16(
                        wf0[fn], hf[fm], acc[fn][fm], 0, 0, 0);
        }
        // ---- ks=1
        {
            bf16x8 hf[4];
#pragma unroll
            for (int f = 0; f < 4; ++f)
                hf[f] = *(const bf16x8*)(Ac + (((4 + quad) * 64) + f * 16 + l15) * 8);
#pragma unroll
            for (int fn = 0; fn < 4; ++fn)
#pragma unroll
                for (int fm = 0; fm < 4; ++fm)
                    acc[fn][fm] = __builtin_amdgcn_mfma_f32_16x16x32_bf16(
                        wf1[fn], hf[fm], acc[fn][fm], 0, 0, 0);
        }
        __syncthreads();   // At[nxt] visible; all At[cur] reads done. VMEM
                           // already consumed -> the vmcnt(0) drain is free.
    }

    // ---- epilogue: relu(acc + b2) -> featL (overlay over At, 32 KiB)
#pragma unroll
    for (int fn = 0; fn < 4; ++fn) {
        const int fcb = wv * 64 + fn * 16 + quad * 4;   // featcol base
        const float4 b2v = *(const float4*)(B2 + slab * 256 + fcb);
        const int o = fcb >> 3, j = fcb & 7;
#pragma unroll
        for (int fm = 0; fm < 4; ++fm) {
            const int smp = fm * 16 + l15;
            const floatx4 v = acc[fn][fm];
            bf16x4 p;
            p[0] = (__bf16)fmaxf(v[0] + b2v.x, 0.f);
            p[1] = (__bf16)fmaxf(v[1] + b2v.y, 0.f);
            p[2] = (__bf16)fmaxf(v[2] + b2v.z, 0.f);
            p[3] = (__bf16)fmaxf(v[3] + b2v.w, 0.f);
            *(bf16x4*)(featL + (o * 64 + smp) * 8 + j) = p;
        }
    }
    __syncthreads();

    // ---- head MFMA: wave wv -> samples wv*16..+15; WHT direct (L2-hot)
    floatx4 hacc[2] = {};
#pragma unroll
    for (int ks2 = 0; ks2 < 8; ++ks2) {
        const bf16x8 fa = *(const bf16x8*)(featL
                             + ((ks2 * 4 + quad) * 64 + wv * 16 + l15) * 8);
#pragma unroll
        for (int t2 = 0; t2 < 2; ++t2) {
            const int r  = t2 * 16 + l15;
            const int og = slab * 32 + ks2 * 4 + quad;
            const bf16x8 wb = *(const bf16x8*)(WHT + (size_t)og * 256 + r * 8);
            hacc[t2] = __builtin_amdgcn_mfma_f32_16x16x32_bf16(
                fa, wb, hacc[t2], 0, 0, 0);
        }
    }

    // ---- atomic scatter: sample = quad*4+reg; emit selected skill's 4 actions
#pragma unroll
    for (int j = 0; j < 4; ++j) {
        const int smp = wv * 16 + quad * 4 + j;
        const int sk  = SK[i0 + smp];
#pragma unroll
        for (int t2 = 0; t2 < 2; ++t2) {
            const int hc = t2 * 16 + l15;
            const int d  = hc - sk * 4;
            if (d >= 0 && d < 4) {
                float v = hacc[t2][j];
                if (slab == 0) v += BH[hc];
                atomicAdd(&OUT[(i0 + smp) * 4 + d], v);
            }
        }
    }
}

extern "C" void kernel_launch(void* const* d_in, const int* in_sizes, int n_in,
                              void* d_out, int out_size, void* d_ws, size_t ws_size,
                              hipStream_t stream) {
    const float* S  = (const float*)d_in[0];
    const int*   SK = (const int*)d_in[1];
    const float* W1 = (const float*)d_in[2];
    const float* B1 = (const float*)d_in[3];
    const float* W2 = (const float*)d_in[4];
    const float* B2 = (const float*)d_in[5];
    const float* WH = (const float*)d_in[6];
    const float* BH = (const float*)d_in[7];

    char* ws = (char*)d_ws;
    __bf16* W2T = (__bf16*)ws;                          // 2 MiB
    __bf16* WHT = (__bf16*)(ws + 2 * 1024 * 1024);      // 64 KiB

    hipLaunchKernelGGL(prep_all, dim3(544), dim3(256), 0, stream,
                       W2, WH, W2T, WHT, (float*)d_out);
    // grid: 1024 sample-groups x 4 slabs; slab = blockIdx>>10 so co-resident
    // blocks share one W2T slab (L2-friendly)
    hipLaunchKernelGGL(policy_main, dim3(4096), dim3(256), 0, stream,
                       S, SK, W1, B1, W2T, B2, WHT, BH, (float*)d_out);
}